// Round 1
// baseline (355.373 us; speedup 1.0000x reference)
//
#include <hip/hip_runtime.h>
#include <math.h>

#define NB   4
#define H1   1056
#define W1   1920
#define H2   528
#define W2   960
#define NBLK 220    // 11*20 blocks per image, both scales
#define NBW  20
#define NF   36
#define NGAM 9801

__device__ __forceinline__ int reflect_idx(int i, int n) {
    if (i < 0) return -i - 1;
    if (i >= n) return 2 * n - i - 1;
    return i;
}

// ---------------- R_GAM table: R_GAM[i] = exp(2*lgamma(2/g)-lgamma(1/g)-lgamma(3/g)), g=0.2+0.001i
__global__ void k_rgam(float* __restrict__ rg) {
    int i = blockIdx.x * 256 + threadIdx.x;
    if (i < NGAM) {
        float g = (float)i * 0.001f + 0.2f;
        rg[i] = expf(2.0f * lgammaf(2.0f / g) - lgammaf(1.0f / g) - lgammaf(3.0f / g));
    }
}

// ---------------- gray: y = round((.299 r + .587 g + .114 b)*255), cropped to 1056 rows
__global__ void k_gray(const float* __restrict__ x, float* __restrict__ y) {
    int idx = blockIdx.x * 256 + threadIdx.x;
    const int total = NB * H1 * W1;
    if (idx >= total) return;
    int w = idx % W1;
    int t = idx / W1;
    int h = t % H1;
    int b = t / H1;
    size_t base = ((size_t)(b * 3) * 1080 + h) * W1 + w;
    float r  = x[base];
    float g  = x[base + (size_t)1080 * W1];
    float bb = x[base + (size_t)2 * 1080 * W1];
    y[idx] = rintf((0.299f * r + 0.587f * g + 0.114f * bb) * 255.0f);
}

// ---------------- MSCN: 7x7 gaussian (computed on the fly in f64, matches numpy), replicate pad
__global__ __launch_bounds__(256) void k_mscn(const float* __restrict__ img,
                                              float* __restrict__ out, int H, int W) {
    __shared__ float  tile[38][38];
    __shared__ double dgw[49];
    __shared__ double dsum;
    __shared__ float  gw[49];
    int tid = threadIdx.y * 16 + threadIdx.x;

    if (tid < 49) {
        int dy = tid / 7 - 3, dx = tid % 7 - 3;
        double s = 7.0 / 6.0;
        dgw[tid] = exp(-(double)(dx * dx + dy * dy) / (2.0 * s * s));
    }
    __syncthreads();
    if (tid == 0) {
        double s = 0.0;
        for (int i = 0; i < 49; i++) s += dgw[i];
        dsum = s;
    }
    __syncthreads();
    if (tid < 49) gw[tid] = (float)(dgw[tid] / dsum);

    int b = blockIdx.z;
    const float* p = img + (size_t)b * H * W;
    int ox0 = blockIdx.x * 32, oy0 = blockIdx.y * 32;
    for (int t = tid; t < 38 * 38; t += 256) {
        int r = t / 38, c = t % 38;
        int gr = oy0 - 3 + r; gr = gr < 0 ? 0 : (gr >= H ? H - 1 : gr);
        int gc = ox0 - 3 + c; gc = gc < 0 ? 0 : (gc >= W ? W - 1 : gc);
        tile[r][c] = p[(size_t)gr * W + gc];
    }
    __syncthreads();

    float* q = out + (size_t)b * H * W;
    for (int sy = 0; sy < 2; sy++)
        for (int sx = 0; sx < 2; sx++) {
            int ly = threadIdx.y + 16 * sy, lx = threadIdx.x + 16 * sx;
            int oy = oy0 + ly, ox = ox0 + lx;
            if (oy < H && ox < W) {
                float s1 = 0.0f, s2 = 0.0f;
                #pragma unroll
                for (int dy = 0; dy < 7; dy++)
                    #pragma unroll
                    for (int dx = 0; dx < 7; dx++) {
                        float v = tile[ly + dy][lx + dx];
                        float w = gw[dy * 7 + dx];
                        s1 += w * v;
                        s2 += w * v * v;
                    }
                float mu  = s1;
                float sig = sqrtf(fabsf(s2 - mu * mu));
                q[(size_t)oy * W + ox] = (tile[ly + 3][lx + 3] - mu) / (sig + 1.0f);
            }
        }
}

// ---------------- bicubic half-resize: fixed 8-tap filter, taps at 2i-3..2i+4, reflect
__device__ const float RW8[8] = {-0.01171875f, -0.03515625f, 0.11328125f, 0.43359375f,
                                  0.43359375f,  0.11328125f, -0.03515625f, -0.01171875f};

__global__ void k_resizeH(const float* __restrict__ y, float* __restrict__ out) {
    int idx = blockIdx.x * 256 + threadIdx.x;
    const int total = NB * H2 * W1;
    if (idx >= total) return;
    int w = idx % W1;
    int t = idx / W1;
    int i = t % H2;
    int b = t / H2;
    const float* p = y + (size_t)b * H1 * W1 + w;
    float acc = 0.0f;
    int base = 2 * i - 3;
    #pragma unroll
    for (int pp = 0; pp < 8; pp++) {
        int r = reflect_idx(base + pp, H1);
        acc += RW8[pp] * (p[(size_t)r * W1] / 255.0f);
    }
    out[idx] = acc;
}

__global__ void k_resizeW(const float* __restrict__ t, float* __restrict__ out) {
    int idx = blockIdx.x * 256 + threadIdx.x;
    const int total = NB * H2 * W2;
    if (idx >= total) return;
    int j = idx % W2;
    int u = idx / W2;
    int i = u % H2;
    int b = u / H2;
    const float* p = t + ((size_t)b * H2 + i) * W1;
    float acc = 0.0f;
    int base = 2 * j - 3;
    #pragma unroll
    for (int pp = 0; pp < 8; pp++) {
        int c = reflect_idx(base + pp, W1);
        acc += RW8[pp] * p[c];
    }
    out[idx] = acc * 255.0f;
}

// ---------------- per-block AGGD features (5 sets: identity + 4 circular-shift products)
template <int BS, int FOFF>
__global__ __launch_bounds__(256) void k_feats(const float* __restrict__ norm,
                                               const float* __restrict__ rgam,
                                               float* __restrict__ feats, int H, int W) {
    __shared__ float x[BS * BS];
    __shared__ float wred[25][4];
    __shared__ float srn[5], sls[5], srs[5];
    __shared__ float rd[256];
    __shared__ int   ri[256];
    __shared__ int   aidx[5];

    int g  = blockIdx.x;          // b*NBLK + r
    int b  = g / NBLK;
    int r  = g % NBLK;
    int bh = r / NBW, bw = r % NBW;
    const float* p = norm + (size_t)b * H * W + (size_t)(bh * BS) * W + (size_t)(bw * BS);
    int tid = threadIdx.x;

    for (int t = tid; t < BS * BS; t += 256) {
        int i = t / BS, j = t % BS;
        x[t] = p[(size_t)i * W + j];
    }
    __syncthreads();

    const int SI[5] = {0, 0, 1, 1, 1};
    const int SJ[5] = {0, 1, 0, 1, -1};
    float sn[5] = {0, 0, 0, 0, 0}, sp[5] = {0, 0, 0, 0, 0};
    float cn[5] = {0, 0, 0, 0, 0}, cp[5] = {0, 0, 0, 0, 0};
    float sa[5] = {0, 0, 0, 0, 0};

    for (int t = tid; t < BS * BS; t += 256) {
        int i = t / BS, j = t % BS;
        float v0 = x[t];
        #pragma unroll
        for (int s = 0; s < 5; s++) {
            float v;
            if (s == 0) v = v0;
            else {
                int ii = i - SI[s]; if (ii < 0) ii += BS;
                int jj = j - SJ[s]; if (jj < 0) jj += BS; if (jj >= BS) jj -= BS;
                v = v0 * x[ii * BS + jj];
            }
            if (v < 0.0f)      { sn[s] += v * v; cn[s] += 1.0f; }
            else if (v > 0.0f) { sp[s] += v * v; cp[s] += 1.0f; }
            sa[s] += fabsf(v);
        }
    }

    int lane = tid & 63, wv = tid >> 6;
    #pragma unroll
    for (int s = 0; s < 5; s++) {
        float vals[5] = {sn[s], sp[s], cn[s], cp[s], sa[s]};
        #pragma unroll
        for (int m = 0; m < 5; m++) {
            float v = vals[m];
            #pragma unroll
            for (int off = 32; off > 0; off >>= 1) v += __shfl_down(v, off, 64);
            if (lane == 0) wred[s * 5 + m][wv] = v;
        }
    }
    __syncthreads();

    if (tid == 0) {
        for (int s = 0; s < 5; s++) {
            float SN = wred[s*5+0][0] + wred[s*5+0][1] + wred[s*5+0][2] + wred[s*5+0][3];
            float SP = wred[s*5+1][0] + wred[s*5+1][1] + wred[s*5+1][2] + wred[s*5+1][3];
            float CN = wred[s*5+2][0] + wred[s*5+2][1] + wred[s*5+2][2] + wred[s*5+2][3];
            float CP = wred[s*5+3][0] + wred[s*5+3][1] + wred[s*5+3][2] + wred[s*5+3][3];
            float SA = wred[s*5+4][0] + wred[s*5+4][1] + wred[s*5+4][2] + wred[s*5+4][3];
            float ls = sqrtf(SN / CN);
            float rs = sqrtf(SP / CP);
            float gh = ls / rs;
            float Nn = (float)(BS * BS);
            float am = SA / Nn;
            float rhat = (am * am) / ((SN + SP) / Nn);
            float g2 = gh * gh;
            float rn = rhat * (g2 * gh + 1.0f) * (gh + 1.0f) / ((g2 + 1.0f) * (g2 + 1.0f));
            srn[s] = rn; sls[s] = ls; srs[s] = rs;
        }
    }
    __syncthreads();

    float bd[5] = {1e30f, 1e30f, 1e30f, 1e30f, 1e30f};
    int   bi[5] = {0, 0, 0, 0, 0};
    for (int idx = tid; idx < NGAM; idx += 256) {
        float rg = rgam[idx];
        #pragma unroll
        for (int s = 0; s < 5; s++) {
            float d = rg - srn[s]; d *= d;
            if (d < bd[s]) { bd[s] = d; bi[s] = idx; }
        }
    }
    for (int s = 0; s < 5; s++) {
        rd[tid] = bd[s]; ri[tid] = bi[s];
        __syncthreads();
        for (int st = 128; st > 0; st >>= 1) {
            if (tid < st) {
                float dv = rd[tid + st]; int iv = ri[tid + st];
                if (dv < rd[tid] || (dv == rd[tid] && iv < ri[tid])) { rd[tid] = dv; ri[tid] = iv; }
            }
            __syncthreads();
        }
        if (tid == 0) aidx[s] = ri[0];
        __syncthreads();
    }

    if (tid == 0) {
        float o[18];
        for (int s = 0; s < 5; s++) {
            float a = (float)aidx[s] * 0.001f + 0.2f;
            float ratio = expf(0.5f * (lgammaf(1.0f / a) - lgammaf(3.0f / a)));
            float bl = sls[s] * ratio;
            float br = srs[s] * ratio;
            if (s == 0) { o[0] = a; o[1] = 0.5f * (bl + br); }
            else {
                float mn = (br - bl) * expf(lgammaf(2.0f / a) - lgammaf(1.0f / a));
                int base = 2 + (s - 1) * 4;
                o[base] = a; o[base + 1] = mn; o[base + 2] = bl; o[base + 3] = br;
            }
        }
        float* fp = feats + (size_t)g * NF + FOFF;
        for (int k = 0; k < 18; k++) fp[k] = o[k];
    }
}

// ---------------- per-batch stats: mean, cov, M=(covp+covd)/2, solve M z = diff, q = diff.z
__global__ __launch_bounds__(256) void k_stats(const float* __restrict__ feats,
                                               const float* __restrict__ mu_pris,
                                               const float* __restrict__ cov_pris,
                                               float* __restrict__ out) {
    __shared__ float  dist[NBLK * NF];
    __shared__ float  mu[NF];
    __shared__ float  cov[NF * NF];
    __shared__ double M[NF][NF + 1];
    __shared__ double fac[NF];
    __shared__ double dd[NF];
    __shared__ double zz[NF];
    __shared__ int    piv;

    int b = blockIdx.x, tid = threadIdx.x;
    for (int t = tid; t < NBLK * NF; t += 256) dist[t] = feats[(size_t)b * NBLK * NF + t];
    __syncthreads();
    if (tid < NF) {
        float s = 0.0f;
        for (int n = 0; n < NBLK; n++) s += dist[n * NF + tid];
        mu[tid] = s / (float)NBLK;
    }
    __syncthreads();
    for (int t = tid; t < NBLK * NF; t += 256) dist[t] -= mu[t % NF];
    __syncthreads();
    for (int t = tid; t < NF * NF; t += 256) {
        int f = t / NF, gg = t % NF;
        float s = 0.0f;
        for (int n = 0; n < NBLK; n++) s += dist[n * NF + f] * dist[n * NF + gg];
        cov[t] = s / (float)(NBLK - 1);
    }
    __syncthreads();
    for (int t = tid; t < NF * NF; t += 256) {
        float m = (cov_pris[(size_t)b * NF * NF + t] + cov[t]) * 0.5f;
        M[t / NF][t % NF] = (double)m;
    }
    if (tid < NF) {
        float d = mu_pris[b * NF + tid] - mu[tid];
        dd[tid] = (double)d;
        M[tid][NF] = (double)d;
    }
    __syncthreads();

    for (int k = 0; k < NF; k++) {
        if (tid == 0) {
            int p = k; double mx = fabs(M[k][k]);
            for (int i = k + 1; i < NF; i++) {
                double a = fabs(M[i][k]);
                if (a > mx) { mx = a; p = i; }
            }
            piv = p;
        }
        __syncthreads();
        int p = piv;
        if (p != k && tid <= NF) { double tt = M[k][tid]; M[k][tid] = M[p][tid]; M[p][tid] = tt; }
        __syncthreads();
        if (tid < NF && tid != k) fac[tid] = M[tid][k] / M[k][k];
        __syncthreads();
        for (int t = tid; t < NF * (NF + 1); t += 256) {
            int i = t / (NF + 1), j = t % (NF + 1);
            if (i != k && j >= k) M[i][j] -= fac[i] * M[k][j];
        }
        __syncthreads();
    }
    if (tid < NF) zz[tid] = M[tid][NF] / M[tid][tid];
    __syncthreads();
    if (tid == 0) {
        double q = 0.0;
        for (int f = 0; f < NF; f++) q += dd[f] * zz[f];
        out[b] = (float)sqrt(q);
    }
}

extern "C" void kernel_launch(void* const* d_in, const int* in_sizes, int n_in,
                              void* d_out, int out_size, void* d_ws, size_t ws_size,
                              hipStream_t stream) {
    const float* x        = (const float*)d_in[0];
    const float* mu_pris  = (const float*)d_in[1];
    const float* cov_pris = (const float*)d_in[2];
    float* out = (float*)d_out;
    float* ws  = (float*)d_ws;

    float* y     = ws;                        // NB*H1*W1 = 8,110,080
    float* nrm   = y + (size_t)NB * H1 * W1;  // 8,110,080 (norm1; later tmpH|half|norm2)
    float* rgam  = nrm + (size_t)NB * H1 * W1;// 9801
    float* feats = rgam + NGAM;               // NB*220*36 = 31,680
    float* tmpH  = nrm;                       // NB*H2*W1 = 4,055,040
    float* half  = tmpH + (size_t)NB * H2 * W1;   // NB*H2*W2 = 2,027,520
    float* nrm2  = half + (size_t)NB * H2 * W2;   // 2,027,520

    k_rgam<<<(NGAM + 255) / 256, 256, 0, stream>>>(rgam);
    k_gray<<<(NB * H1 * W1 + 255) / 256, 256, 0, stream>>>(x, y);

    dim3 thr(16, 16);
    k_mscn<<<dim3(W1 / 32, H1 / 32, NB), thr, 0, stream>>>(y, nrm, H1, W1);
    k_feats<96, 0><<<NB * NBLK, 256, 0, stream>>>(nrm, rgam, feats, H1, W1);

    k_resizeH<<<(NB * H2 * W1 + 255) / 256, 256, 0, stream>>>(y, tmpH);
    k_resizeW<<<(NB * H2 * W2 + 255) / 256, 256, 0, stream>>>(tmpH, half);

    k_mscn<<<dim3(W2 / 32, (H2 + 31) / 32, NB), thr, 0, stream>>>(half, nrm2, H2, W2);
    k_feats<48, 18><<<NB * NBLK, 256, 0, stream>>>(nrm2, rgam, feats, H2, W2);

    k_stats<<<NB, 256, 0, stream>>>(feats, mu_pris, cov_pris, out);
}

// Round 2
// 276.943 us; speedup vs baseline: 1.2832x; 1.2832x over previous
//
#include <hip/hip_runtime.h>
#include <math.h>

#define NB   4
#define H1   1056
#define W1   1920
#define H2   528
#define W2   960
#define NBLK 220    // 11*20 blocks per image, both scales
#define NBW  20
#define NF   36
#define NGAM 9801

__device__ __forceinline__ int reflect_idx(int i, int n) {
    if (i < 0) return -i - 1;
    if (i >= n) return 2 * n - i - 1;
    return i;
}

// ---------------- R_GAM table: R_GAM[i] = exp(2*lgamma(2/g)-lgamma(1/g)-lgamma(3/g)), g=0.2+0.001i
__global__ void k_rgam(float* __restrict__ rg) {
    int i = blockIdx.x * 256 + threadIdx.x;
    if (i < NGAM) {
        float g = (float)i * 0.001f + 0.2f;
        rg[i] = expf(2.0f * lgammaf(2.0f / g) - lgammaf(1.0f / g) - lgammaf(3.0f / g));
    }
}

// ---------------- gray: y = round((.299 r + .587 g + .114 b)*255), cropped to 1056 rows
__global__ void k_gray(const float* __restrict__ x, float* __restrict__ y) {
    int idx = blockIdx.x * 256 + threadIdx.x;
    const int total = NB * H1 * W1;
    if (idx >= total) return;
    int w = idx % W1;
    int t = idx / W1;
    int h = t % H1;
    int b = t / H1;
    size_t base = ((size_t)(b * 3) * 1080 + h) * W1 + w;
    float r  = x[base];
    float g  = x[base + (size_t)1080 * W1];
    float bb = x[base + (size_t)2 * 1080 * W1];
    y[idx] = rintf((0.299f * r + 0.587f * g + 0.114f * bb) * 255.0f);
}

// ---------------- MSCN: separable 7-tap Gaussian (1D weights in f64), replicate pad
// block = (32,8); output tile 32x32; strides chosen for free 2-way LDS banking
__global__ __launch_bounds__(256) void k_mscn(const float* __restrict__ img,
                                              float* __restrict__ out, int H, int W) {
    __shared__ float tile[38][40];   // stride 40: wave(2rowsx32col) -> 2-way (free)
    __shared__ float h1[38][33];     // stride 33: 2-way (free)
    __shared__ float h2[38][33];
    __shared__ float gw1[7];

    int tx = threadIdx.x;            // 0..31
    int ty = threadIdx.y;            // 0..7
    int tid = ty * 32 + tx;

    if (tid < 7) {
        double s = 7.0 / 6.0;
        double sum = 0.0;
        #pragma unroll
        for (int k = 0; k < 7; k++) sum += exp(-(double)((k - 3) * (k - 3)) / (2.0 * s * s));
        double e = exp(-(double)((tid - 3) * (tid - 3)) / (2.0 * s * s));
        gw1[tid] = (float)(e / sum);
    }

    int b = blockIdx.z;
    const float* p = img + (size_t)b * H * W;
    int ox0 = blockIdx.x * 32, oy0 = blockIdx.y * 32;

    for (int t = tid; t < 38 * 38; t += 256) {
        int r = t / 38, c = t % 38;
        int gr = oy0 - 3 + r; gr = gr < 0 ? 0 : (gr >= H ? H - 1 : gr);
        int gc = ox0 - 3 + c; gc = gc < 0 ? 0 : (gc >= W ? W - 1 : gc);
        tile[r][c] = p[(size_t)gr * W + gc];
    }
    __syncthreads();

    // horizontal pass: 38 rows x 32 cols
    for (int t = tid; t < 38 * 32; t += 256) {
        int r = t / 32, c = t % 32;
        float s1 = 0.0f, s2 = 0.0f;
        #pragma unroll
        for (int k = 0; k < 7; k++) {
            float v = tile[r][c + k];
            float w = gw1[k];
            s1 += w * v;
            s2 += w * v * v;
        }
        h1[r][c] = s1;
        h2[r][c] = s2;
    }
    __syncthreads();

    // vertical pass: 4 output rows per thread
    float* q = out + (size_t)b * H * W;
    #pragma unroll
    for (int sy = 0; sy < 4; sy++) {
        int ly = ty + 8 * sy;
        int oy = oy0 + ly, ox = ox0 + tx;
        if (oy < H && ox < W) {
            float s1 = 0.0f, s2 = 0.0f;
            #pragma unroll
            for (int k = 0; k < 7; k++) {
                float w = gw1[k];
                s1 += w * h1[ly + k][tx];
                s2 += w * h2[ly + k][tx];
            }
            float mu  = s1;
            float sig = sqrtf(fabsf(s2 - mu * mu));
            q[(size_t)oy * W + ox] = (tile[ly + 3][tx + 3] - mu) / (sig + 1.0f);
        }
    }
}

// ---------------- bicubic half-resize: fixed 8-tap filter, taps at 2i-3..2i+4, reflect
__device__ const float RW8[8] = {-0.01171875f, -0.03515625f, 0.11328125f, 0.43359375f,
                                  0.43359375f,  0.11328125f, -0.03515625f, -0.01171875f};

__global__ void k_resizeH(const float* __restrict__ y, float* __restrict__ out) {
    int idx = blockIdx.x * 256 + threadIdx.x;
    const int total = NB * H2 * W1;
    if (idx >= total) return;
    int w = idx % W1;
    int t = idx / W1;
    int i = t % H2;
    int b = t / H2;
    const float* p = y + (size_t)b * H1 * W1 + w;
    float acc = 0.0f;
    int base = 2 * i - 3;
    #pragma unroll
    for (int pp = 0; pp < 8; pp++) {
        int r = reflect_idx(base + pp, H1);
        acc += RW8[pp] * (p[(size_t)r * W1] / 255.0f);
    }
    out[idx] = acc;
}

__global__ void k_resizeW(const float* __restrict__ t, float* __restrict__ out) {
    int idx = blockIdx.x * 256 + threadIdx.x;
    const int total = NB * H2 * W2;
    if (idx >= total) return;
    int j = idx % W2;
    int u = idx / W2;
    int i = u % H2;
    int b = u / W2 == 0 ? u / H2 : u / H2;  // b = u / H2
    b = u / H2;
    const float* p = t + ((size_t)b * H2 + i) * W1;
    float acc = 0.0f;
    int base = 2 * j - 3;
    #pragma unroll
    for (int pp = 0; pp < 8; pp++) {
        int c = reflect_idx(base + pp, W1);
        acc += RW8[pp] * p[c];
    }
    out[idx] = acc * 255.0f;
}

// ---------------- per-block AGGD features (5 sets: identity + 4 circular-shift products)
template <int BS, int FOFF>
__global__ __launch_bounds__(256) void k_feats(const float* __restrict__ norm,
                                               const float* __restrict__ rgam,
                                               float* __restrict__ feats, int H, int W) {
    __shared__ float x[BS * BS];
    __shared__ float wred[25][4];
    __shared__ float srn[5], sls[5], srs[5];
    __shared__ float wargd[5][4];
    __shared__ int   wargi[5][4];
    __shared__ int   aidx[5];

    int g  = blockIdx.x;          // b*NBLK + r
    int b  = g / NBLK;
    int r  = g % NBLK;
    int bh = r / NBW, bw = r % NBW;
    const float* p = norm + (size_t)b * H * W + (size_t)(bh * BS) * W + (size_t)(bw * BS);
    int tid = threadIdx.x;

    for (int t = tid; t < BS * BS; t += 256) {
        int i = t / BS, j = t % BS;
        x[t] = p[(size_t)i * W + j];
    }
    __syncthreads();

    const int SI[5] = {0, 0, 1, 1, 1};
    const int SJ[5] = {0, 1, 0, 1, -1};
    float sn[5] = {0, 0, 0, 0, 0}, sp[5] = {0, 0, 0, 0, 0};
    float cn[5] = {0, 0, 0, 0, 0}, cp[5] = {0, 0, 0, 0, 0};
    float sa[5] = {0, 0, 0, 0, 0};

    for (int t = tid; t < BS * BS; t += 256) {
        int i = t / BS, j = t % BS;
        float v0 = x[t];
        #pragma unroll
        for (int s = 0; s < 5; s++) {
            float v;
            if (s == 0) v = v0;
            else {
                int ii = i - SI[s]; if (ii < 0) ii += BS;
                int jj = j - SJ[s]; if (jj < 0) jj += BS; if (jj >= BS) jj -= BS;
                v = v0 * x[ii * BS + jj];
            }
            if (v < 0.0f)      { sn[s] += v * v; cn[s] += 1.0f; }
            else if (v > 0.0f) { sp[s] += v * v; cp[s] += 1.0f; }
            sa[s] += fabsf(v);
        }
    }

    int lane = tid & 63, wv = tid >> 6;
    #pragma unroll
    for (int s = 0; s < 5; s++) {
        float vals[5] = {sn[s], sp[s], cn[s], cp[s], sa[s]};
        #pragma unroll
        for (int m = 0; m < 5; m++) {
            float v = vals[m];
            #pragma unroll
            for (int off = 32; off > 0; off >>= 1) v += __shfl_down(v, off, 64);
            if (lane == 0) wred[s * 5 + m][wv] = v;
        }
    }
    __syncthreads();

    if (tid == 0) {
        for (int s = 0; s < 5; s++) {
            float SN = wred[s*5+0][0] + wred[s*5+0][1] + wred[s*5+0][2] + wred[s*5+0][3];
            float SP = wred[s*5+1][0] + wred[s*5+1][1] + wred[s*5+1][2] + wred[s*5+1][3];
            float CN = wred[s*5+2][0] + wred[s*5+2][1] + wred[s*5+2][2] + wred[s*5+2][3];
            float CP = wred[s*5+3][0] + wred[s*5+3][1] + wred[s*5+3][2] + wred[s*5+3][3];
            float SA = wred[s*5+4][0] + wred[s*5+4][1] + wred[s*5+4][2] + wred[s*5+4][3];
            float ls = sqrtf(SN / CN);
            float rs = sqrtf(SP / CP);
            float gh = ls / rs;
            float Nn = (float)(BS * BS);
            float am = SA / Nn;
            float rhat = (am * am) / ((SN + SP) / Nn);
            float g2 = gh * gh;
            float rn = rhat * (g2 * gh + 1.0f) * (gh + 1.0f) / ((g2 + 1.0f) * (g2 + 1.0f));
            srn[s] = rn; sls[s] = ls; srs[s] = rs;
        }
    }
    __syncthreads();

    float bd[5] = {1e30f, 1e30f, 1e30f, 1e30f, 1e30f};
    int   bi[5] = {0, 0, 0, 0, 0};
    for (int idx = tid; idx < NGAM; idx += 256) {
        float rg = rgam[idx];
        #pragma unroll
        for (int s = 0; s < 5; s++) {
            float d = rg - srn[s]; d *= d;
            if (d < bd[s]) { bd[s] = d; bi[s] = idx; }
        }
    }
    // wave-level argmin (ties -> smaller index, matching jnp.argmin first-min)
    #pragma unroll
    for (int s = 0; s < 5; s++) {
        float d = bd[s];
        int   i = bi[s];
        #pragma unroll
        for (int off = 32; off > 0; off >>= 1) {
            float od = __shfl_down(d, off, 64);
            int   oi = __shfl_down(i, off, 64);
            if (od < d || (od == d && oi < i)) { d = od; i = oi; }
        }
        if (lane == 0) { wargd[s][wv] = d; wargi[s][wv] = i; }
    }
    __syncthreads();

    if (tid == 0) {
        float o[18];
        for (int s = 0; s < 5; s++) {
            float d = wargd[s][0]; int ix = wargi[s][0];
            for (int w2 = 1; w2 < 4; w2++) {
                float od = wargd[s][w2]; int oi = wargi[s][w2];
                if (od < d || (od == d && oi < ix)) { d = od; ix = oi; }
            }
            aidx[s] = ix;
        }
        for (int s = 0; s < 5; s++) {
            float a = (float)aidx[s] * 0.001f + 0.2f;
            float ratio = expf(0.5f * (lgammaf(1.0f / a) - lgammaf(3.0f / a)));
            float bl = sls[s] * ratio;
            float br = srs[s] * ratio;
            if (s == 0) { o[0] = a; o[1] = 0.5f * (bl + br); }
            else {
                float mn = (br - bl) * expf(lgammaf(2.0f / a) - lgammaf(1.0f / a));
                int base = 2 + (s - 1) * 4;
                o[base] = a; o[base + 1] = mn; o[base + 2] = bl; o[base + 3] = br;
            }
        }
        float* fp = feats + (size_t)g * NF + FOFF;
        for (int k = 0; k < 18; k++) fp[k] = o[k];
    }
}

// ---------------- per-batch stats: mean, cov, M=(covp+covd)/2, solve M z = diff, q = diff.z
__global__ __launch_bounds__(256) void k_stats(const float* __restrict__ feats,
                                               const float* __restrict__ mu_pris,
                                               const float* __restrict__ cov_pris,
                                               float* __restrict__ out) {
    __shared__ float  dist[NBLK * NF];
    __shared__ float  mu[NF];
    __shared__ float  cov[NF * NF];
    __shared__ double M[NF][NF + 1];
    __shared__ double fac[NF];
    __shared__ double dd[NF];
    __shared__ double zz[NF];
    __shared__ int    piv;

    int b = blockIdx.x, tid = threadIdx.x;
    for (int t = tid; t < NBLK * NF; t += 256) dist[t] = feats[(size_t)b * NBLK * NF + t];
    __syncthreads();
    if (tid < NF) {
        float s = 0.0f;
        for (int n = 0; n < NBLK; n++) s += dist[n * NF + tid];
        mu[tid] = s / (float)NBLK;
    }
    __syncthreads();
    for (int t = tid; t < NBLK * NF; t += 256) dist[t] -= mu[t % NF];
    __syncthreads();
    for (int t = tid; t < NF * NF; t += 256) {
        int f = t / NF, gg = t % NF;
        float s = 0.0f;
        for (int n = 0; n < NBLK; n++) s += dist[n * NF + f] * dist[n * NF + gg];
        cov[t] = s / (float)(NBLK - 1);
    }
    __syncthreads();
    for (int t = tid; t < NF * NF; t += 256) {
        float m = (cov_pris[(size_t)b * NF * NF + t] + cov[t]) * 0.5f;
        M[t / NF][t % NF] = (double)m;
    }
    if (tid < NF) {
        float d = mu_pris[b * NF + tid] - mu[tid];
        dd[tid] = (double)d;
        M[tid][NF] = (double)d;
    }
    __syncthreads();

    for (int k = 0; k < NF; k++) {
        if (tid == 0) {
            int p = k; double mx = fabs(M[k][k]);
            for (int i = k + 1; i < NF; i++) {
                double a = fabs(M[i][k]);
                if (a > mx) { mx = a; p = i; }
            }
            piv = p;
        }
        __syncthreads();
        int p = piv;
        if (p != k && tid <= NF) { double tt = M[k][tid]; M[k][tid] = M[p][tid]; M[p][tid] = tt; }
        __syncthreads();
        if (tid < NF && tid != k) fac[tid] = M[tid][k] / M[k][k];
        __syncthreads();
        for (int t = tid; t < NF * (NF + 1); t += 256) {
            int i = t / (NF + 1), j = t % (NF + 1);
            if (i != k && j >= k) M[i][j] -= fac[i] * M[k][j];
        }
        __syncthreads();
    }
    if (tid < NF) zz[tid] = M[tid][NF] / M[tid][tid];
    __syncthreads();
    if (tid == 0) {
        double q = 0.0;
        for (int f = 0; f < NF; f++) q += dd[f] * zz[f];
        out[b] = (float)sqrt(q);
    }
}

extern "C" void kernel_launch(void* const* d_in, const int* in_sizes, int n_in,
                              void* d_out, int out_size, void* d_ws, size_t ws_size,
                              hipStream_t stream) {
    const float* x        = (const float*)d_in[0];
    const float* mu_pris  = (const float*)d_in[1];
    const float* cov_pris = (const float*)d_in[2];
    float* out = (float*)d_out;
    float* ws  = (float*)d_ws;

    float* y     = ws;                        // NB*H1*W1 = 8,110,080
    float* nrm   = y + (size_t)NB * H1 * W1;  // 8,110,080 (norm1; later tmpH|half|norm2)
    float* rgam  = nrm + (size_t)NB * H1 * W1;// 9801
    float* feats = rgam + NGAM;               // NB*220*36 = 31,680
    float* tmpH  = nrm;                       // NB*H2*W1 = 4,055,040
    float* half  = tmpH + (size_t)NB * H2 * W1;   // NB*H2*W2 = 2,027,520
    float* nrm2  = half + (size_t)NB * H2 * W2;   // 2,027,520

    k_rgam<<<(NGAM + 255) / 256, 256, 0, stream>>>(rgam);
    k_gray<<<(NB * H1 * W1 + 255) / 256, 256, 0, stream>>>(x, y);

    dim3 thr(32, 8);
    k_mscn<<<dim3(W1 / 32, H1 / 32, NB), thr, 0, stream>>>(y, nrm, H1, W1);
    k_feats<96, 0><<<NB * NBLK, 256, 0, stream>>>(nrm, rgam, feats, H1, W1);

    k_resizeH<<<(NB * H2 * W1 + 255) / 256, 256, 0, stream>>>(y, tmpH);
    k_resizeW<<<(NB * H2 * W2 + 255) / 256, 256, 0, stream>>>(tmpH, half);

    k_mscn<<<dim3(W2 / 32, (H2 + 31) / 32, NB), thr, 0, stream>>>(half, nrm2, H2, W2);
    k_feats<48, 18><<<NB * NBLK, 256, 0, stream>>>(nrm2, rgam, feats, H2, W2);

    k_stats<<<NB, 256, 0, stream>>>(feats, mu_pris, cov_pris, out);
}